// Round 1
// baseline (177.814 us; speedup 1.0000x reference)
//
#include <hip/hip_runtime.h>

#define SEQ 20
#define DK  64
#define NG  16          // float4 groups per 64-float row
#define SSTRIDE 24      // padded floats per score row (16B-aligned rows)

__global__ __launch_bounds__(256)
void fused_deatt_kernel(const float* __restrict__ Qg,
                        const float* __restrict__ Kg,
                        const float* __restrict__ Vg,
                        const float* __restrict__ Mg,
                        float* __restrict__ deAtt,
                        float* __restrict__ attnOut)
{
    // Q: swizzle g^(r&3); K: swizzle g^((r>>1)&7); V: linear.
    __shared__ float4 sQ[SEQ * NG];
    __shared__ float4 sK[SEQ * NG];
    __shared__ float4 sV[SEQ * NG];
    __shared__ __align__(16) float sS[SEQ * SSTRIDE];
    __shared__ float sRinv[SEQ];

    const int bh  = blockIdx.x;
    const int tid = threadIdx.x;
    const size_t base = (size_t)bh * (SEQ * DK);

    const float4* gq = reinterpret_cast<const float4*>(Qg + base);
    const float4* gk = reinterpret_cast<const float4*>(Kg + base);
    const float4* gv = reinterpret_cast<const float4*>(Vg + base);

    // ---------------- Phase A: stage Q,K,V into LDS ----------------
    for (int i = tid; i < SEQ * NG; i += 256) {
        const int r = i >> 4;
        const int g = i & 15;
        sQ[(r << 4) | (g ^ (r & 3))]        = gq[i];
        sK[(r << 4) | (g ^ ((r >> 1) & 7))] = gk[i];
        sV[i]                               = gv[i];
    }
    __syncthreads();

    // ---------------- Phase B: exp-scores * mask, 2x2 tiles ----------------
    if (tid < 100) {
        const int qt = tid / 10;
        const int kt = tid - qt * 10;
        const int q0 = qt * 2, k0 = kt * 2;
        float a00 = 0.f, a01 = 0.f, a10 = 0.f, a11 = 0.f;
        #pragma unroll
        for (int g = 0; g < NG; ++g) {
            const float4 qa = sQ[(q0 << 4)       | (g ^ (q0 & 3))];
            const float4 qb = sQ[((q0 + 1) << 4) | (g ^ ((q0 + 1) & 3))];
            const float4 ka = sK[(k0 << 4)       | (g ^ (kt & 7))];
            const float4 kb = sK[((k0 + 1) << 4) | (g ^ (kt & 7))];
            a00 += qa.x * ka.x; a00 += qa.y * ka.y; a00 += qa.z * ka.z; a00 += qa.w * ka.w;
            a01 += qa.x * kb.x; a01 += qa.y * kb.y; a01 += qa.z * kb.z; a01 += qa.w * kb.w;
            a10 += qb.x * ka.x; a10 += qb.y * ka.y; a10 += qb.z * ka.z; a10 += qb.w * ka.w;
            a11 += qb.x * kb.x; a11 += qb.y * kb.y; a11 += qb.z * kb.z; a11 += qb.w * kb.w;
        }
        const float scale = 0.125f;   // 1/sqrt(64)
        const float* m = Mg + (size_t)bh * (SEQ * SEQ);
        const float2 m0 = *reinterpret_cast<const float2*>(m + q0 * SEQ + k0);
        const float2 m1 = *reinterpret_cast<const float2*>(m + (q0 + 1) * SEQ + k0);
        sS[q0 * SSTRIDE + k0]           = expf(a00 * scale) * m0.x;
        sS[q0 * SSTRIDE + k0 + 1]       = expf(a01 * scale) * m0.y;
        sS[(q0 + 1) * SSTRIDE + k0]     = expf(a10 * scale) * m1.x;
        sS[(q0 + 1) * SSTRIDE + k0 + 1] = expf(a11 * scale) * m1.y;
    }
    __syncthreads();

    // ---------------- Phase C: row sums -> 1/(sum+eps) ----------------
    if (tid < SEQ) {
        float s = 0.f;
        #pragma unroll
        for (int k = 0; k < SEQ; ++k) s += sS[tid * SSTRIDE + k];
        sRinv[tid] = 1.0f / (s + 1e-8f);
    }
    __syncthreads();

    // ---------------- Phase D: write normalized attn ----------------
    // 400 floats per bh = 100 float4; rows are 20 floats = 5 float4 (never split).
    if (tid < 100) {
        const int qq = tid / 5;
        const int g4 = (tid - qq * 5) * 4;
        const float4 s = *reinterpret_cast<const float4*>(&sS[qq * SSTRIDE + g4]);
        const float r = sRinv[qq];
        float4 o; o.x = s.x * r; o.y = s.y * r; o.z = s.z * r; o.w = s.w * r;
        *reinterpret_cast<float4*>(attnOut + (size_t)bh * (SEQ * SEQ) + qq * SEQ + g4) = o;
    }

    // ---------------- Phase E: deAtt = (attn + Md) @ V ----------------
    if (tid < 160) {
        const int qp = tid >> 4;      // 0..9
        const int dg = tid & 15;      // float4 column group 0..15
        const int q0 = qp * 2, q1 = q0 + 1;
        const float r0 = sRinv[q0], r1 = sRinv[q1];
        float4 acc0 = {0.f, 0.f, 0.f, 0.f};
        float4 acc1 = {0.f, 0.f, 0.f, 0.f};
        #pragma unroll
        for (int k4 = 0; k4 < 5; ++k4) {
            const int kb = k4 * 4;
            const float4 s0 = *reinterpret_cast<const float4*>(&sS[q0 * SSTRIDE + kb]);
            const float4 s1 = *reinterpret_cast<const float4*>(&sS[q1 * SSTRIDE + kb]);
            const float4 v0 = sV[(kb + 0) * NG + dg];
            const float4 v1 = sV[(kb + 1) * NG + dg];
            const float4 v2 = sV[(kb + 2) * NG + dg];
            const float4 v3 = sV[(kb + 3) * NG + dg];
            // Md(q,k) = -|q-k|
            int d;
            d = q0 - (kb + 0); const float w00 = s0.x * r0 - (float)(d < 0 ? -d : d);
            d = q0 - (kb + 1); const float w01 = s0.y * r0 - (float)(d < 0 ? -d : d);
            d = q0 - (kb + 2); const float w02 = s0.z * r0 - (float)(d < 0 ? -d : d);
            d = q0 - (kb + 3); const float w03 = s0.w * r0 - (float)(d < 0 ? -d : d);
            d = q1 - (kb + 0); const float w10 = s1.x * r1 - (float)(d < 0 ? -d : d);
            d = q1 - (kb + 1); const float w11 = s1.y * r1 - (float)(d < 0 ? -d : d);
            d = q1 - (kb + 2); const float w12 = s1.z * r1 - (float)(d < 0 ? -d : d);
            d = q1 - (kb + 3); const float w13 = s1.w * r1 - (float)(d < 0 ? -d : d);
            acc0.x += w00 * v0.x; acc0.y += w00 * v0.y; acc0.z += w00 * v0.z; acc0.w += w00 * v0.w;
            acc0.x += w01 * v1.x; acc0.y += w01 * v1.y; acc0.z += w01 * v1.z; acc0.w += w01 * v1.w;
            acc0.x += w02 * v2.x; acc0.y += w02 * v2.y; acc0.z += w02 * v2.z; acc0.w += w02 * v2.w;
            acc0.x += w03 * v3.x; acc0.y += w03 * v3.y; acc0.z += w03 * v3.z; acc0.w += w03 * v3.w;
            acc1.x += w10 * v0.x; acc1.y += w10 * v0.y; acc1.z += w10 * v0.z; acc1.w += w10 * v0.w;
            acc1.x += w11 * v1.x; acc1.y += w11 * v1.y; acc1.z += w11 * v1.z; acc1.w += w11 * v1.w;
            acc1.x += w12 * v2.x; acc1.y += w12 * v2.y; acc1.z += w12 * v2.z; acc1.w += w12 * v2.w;
            acc1.x += w13 * v3.x; acc1.y += w13 * v3.y; acc1.z += w13 * v3.z; acc1.w += w13 * v3.w;
        }
        reinterpret_cast<float4*>(deAtt + base + q0 * DK)[dg] = acc0;
        reinterpret_cast<float4*>(deAtt + base + q1 * DK)[dg] = acc1;
    }
}

extern "C" void kernel_launch(void* const* d_in, const int* in_sizes, int n_in,
                              void* d_out, int out_size, void* d_ws, size_t ws_size,
                              hipStream_t stream) {
    const float* Q = (const float*)d_in[0];
    const float* K = (const float*)d_in[1];
    const float* V = (const float*)d_in[2];
    const float* M = (const float*)d_in[3];
    float* out = (float*)d_out;

    const int nbh = in_sizes[0] / (SEQ * DK);   // B*H = 8192
    float* deAtt = out;                              // [nbh, SEQ, DK]
    float* attn  = out + (size_t)nbh * SEQ * DK;     // [nbh, SEQ, SEQ]

    fused_deatt_kernel<<<nbh, 256, 0, stream>>>(Q, K, V, M, deAtt, attn);
}